// Round 2
// baseline (559.529 us; speedup 1.0000x reference)
//
#include <hip/hip_runtime.h>
#include <math.h>

#define IN_DIM 128
#define OUT_DIM 64
#define NEG_SLOPE 0.2f

// ---------------------------------------------------------------- GEMM
// h = X@W, el = h@a_l, er = h@a_r.
// One wave computes 4 rows (lane = output column); W read from LDS is
// amortized 4x vs baseline (the LDS-BW bottleneck).
__global__ __launch_bounds__(256) void gemm_kernel(
        const float* __restrict__ X, const float* __restrict__ W,
        const float* __restrict__ a_l, const float* __restrict__ a_r,
        float* __restrict__ h, float* __restrict__ el, float* __restrict__ er, int n)
{
    __shared__ float Wl[IN_DIM * OUT_DIM];    // 32 KB
    __shared__ float Xl[16][IN_DIM];          // 8 KB
    const int tid  = threadIdx.x;
    const int wave = tid >> 6;
    const int lane = tid & 63;

    // coop load W (float4, coalesced)
    const float4* W4 = (const float4*)W;
    #pragma unroll
    for (int i = tid; i < IN_DIM * OUT_DIM / 4; i += 256)
        ((float4*)Wl)[i] = W4[i];

    const int row0 = blockIdx.x * 16 + wave * 4;

    // stage this wave's 4 X rows (float2 per lane, coalesced)
    #pragma unroll
    for (int i = 0; i < 4; ++i) {
        int r = row0 + i;
        if (r < n) {
            float2 v = ((const float2*)(X + (size_t)r * IN_DIM))[lane];
            Xl[wave * 4 + i][lane * 2]     = v.x;
            Xl[wave * 4 + i][lane * 2 + 1] = v.y;
        }
    }
    __syncthreads();   // W visibility

    float acc[4] = {0.f, 0.f, 0.f, 0.f};
    #pragma unroll 8
    for (int k = 0; k < IN_DIM; ++k) {
        float w = Wl[k * OUT_DIM + lane];          // conflict-free (2-way alias ok)
        #pragma unroll
        for (int i = 0; i < 4; ++i)
            acc[i] += Xl[wave * 4 + i][k] * w;     // LDS broadcast
    }

    const float alv = a_l[lane];
    const float arv = a_r[lane];
    #pragma unroll
    for (int i = 0; i < 4; ++i) {
        int r = row0 + i;
        if (r >= n) continue;
        h[(size_t)r * OUT_DIM + lane] = acc[i];
        float vl = acc[i] * alv;
        float vr = acc[i] * arv;
        #pragma unroll
        for (int off = 32; off > 0; off >>= 1) {
            vl += __shfl_xor(vl, off);
            vr += __shfl_xor(vr, off);
        }
        if (lane == 0) { el[r] = vl; er[r] = vr; }
    }
}

// ---------------------------------------------------------------- CSR build
__global__ void degree_kernel(const int* __restrict__ dst, int* __restrict__ deg, int e) {
    int i = blockIdx.x * blockDim.x + threadIdx.x;
    if (i < e) atomicAdd(&deg[dst[i]], 1);
}

// single-block exclusive scan of deg[0..n) -> offsets[0..n], cursor copy
__global__ __launch_bounds__(1024) void scan_kernel(
        const int* __restrict__ deg, int* __restrict__ offsets,
        int* __restrict__ cursor, int n)
{
    __shared__ int partial[1024];
    const int t = threadIdx.x;
    const int chunk = (n + 1023) / 1024;
    const int begin  = t * chunk;
    const int finish = min(begin + chunk, n);

    int sum = 0;
    for (int i = begin; i < finish; ++i) sum += deg[i];
    partial[t] = sum;
    __syncthreads();

    // Hillis-Steele inclusive scan over 1024 partials
    for (int off = 1; off < 1024; off <<= 1) {
        int add = (t >= off) ? partial[t - off] : 0;
        __syncthreads();
        partial[t] += add;
        __syncthreads();
    }
    int excl = partial[t] - sum;

    int run = excl;
    for (int i = begin; i < finish; ++i) {
        int d = deg[i];
        offsets[i] = run;
        cursor[i]  = run;
        run += d;
    }
    if (begin < n && finish == n) offsets[n] = run;   // == E
}

__global__ void scatter_kernel(
        const int* __restrict__ src, const int* __restrict__ dst,
        int* __restrict__ cursor, int* __restrict__ esrc, int e)
{
    int i = blockIdx.x * blockDim.x + threadIdx.x;
    if (i >= e) return;
    int p = atomicAdd(&cursor[dst[i]], 1);
    esrc[p] = src[i];
}

// ---------------------------------------------------------------- fused softmax + aggregate
// One wave per destination node. lane = output channel.
__global__ __launch_bounds__(256) void gat_node_kernel(
        const int* __restrict__ esrc, const int* __restrict__ offsets,
        const float* __restrict__ el, const float* __restrict__ er,
        const float* __restrict__ h, float* __restrict__ out, int n)
{
    const int node = blockIdx.x * 4 + (threadIdx.x >> 6);
    const int lane = threadIdx.x & 63;
    if (node >= n) return;

    const int start = offsets[node];
    const int deg   = offsets[node + 1] - start;

    float acc = 0.f;
    if (deg > 0) {
        const float erd = er[node];
        if (deg <= 64) {
            // fast path: lane j owns edge j
            int   s = 0;
            float x = -INFINITY;
            if (lane < deg) {
                s = esrc[start + lane];
                x = el[s] + erd;
                x = (x > 0.f) ? x : NEG_SLOPE * x;
            }
            float m = x;
            #pragma unroll
            for (int off = 32; off > 0; off >>= 1) m = fmaxf(m, __shfl_xor(m, off));
            float ex = (lane < deg) ? __expf(x - m) : 0.f;
            float dsum = ex;
            #pragma unroll
            for (int off = 32; off > 0; off >>= 1) dsum += __shfl_xor(dsum, off);
            const float inv = 1.f / dsum;   // dsum >= 1 (max lane contributes 1)

            for (int j = 0; j < deg; ++j) {
                float a  = __shfl(ex, j) * inv;
                int   sj = __shfl(s, j);
                acc += a * h[(size_t)sj * OUT_DIM + lane];
            }
        } else {
            // general chunked path (rare: deg > 64)
            float m = -INFINITY;
            for (int base = 0; base < deg; base += 64) {
                int idx = base + lane;
                if (idx < deg) {
                    int ss = esrc[start + idx];
                    float xx = el[ss] + erd;
                    xx = (xx > 0.f) ? xx : NEG_SLOPE * xx;
                    m = fmaxf(m, xx);
                }
            }
            #pragma unroll
            for (int off = 32; off > 0; off >>= 1) m = fmaxf(m, __shfl_xor(m, off));

            float dsum = 0.f;
            for (int base = 0; base < deg; base += 64) {
                int idx = base + lane;
                if (idx < deg) {
                    int ss = esrc[start + idx];
                    float xx = el[ss] + erd;
                    xx = (xx > 0.f) ? xx : NEG_SLOPE * xx;
                    dsum += __expf(xx - m);
                }
            }
            #pragma unroll
            for (int off = 32; off > 0; off >>= 1) dsum += __shfl_xor(dsum, off);
            const float inv = 1.f / dsum;

            for (int base = 0; base < deg; base += 64) {
                int idx = base + lane;
                int   ss = 0;
                float ex = 0.f;
                if (idx < deg) {
                    ss = esrc[start + idx];
                    float xx = el[ss] + erd;
                    xx = (xx > 0.f) ? xx : NEG_SLOPE * xx;
                    ex = __expf(xx - m);
                }
                int cnt = min(64, deg - base);
                for (int j = 0; j < cnt; ++j) {
                    float a  = __shfl(ex, j) * inv;
                    int   sj = __shfl(ss, j);
                    acc += a * h[(size_t)sj * OUT_DIM + lane];
                }
            }
        }
    }
    out[(size_t)node * OUT_DIM + lane] = acc;
}

// ---------------------------------------------------------------- launch
extern "C" void kernel_launch(void* const* d_in, const int* in_sizes, int n_in,
                              void* d_out, int out_size, void* d_ws, size_t ws_size,
                              hipStream_t stream) {
    const float* X   = (const float*)d_in[0];
    const int*   ei  = (const int*)  d_in[1];
    const float* W   = (const float*)d_in[2];
    const float* a_l = (const float*)d_in[3];
    const float* a_r = (const float*)d_in[4];
    float* out = (float*)d_out;

    const int n = in_sizes[0] / IN_DIM;   // 100000
    const int e = in_sizes[1] / 2;        // 1000000
    const int* src = ei;
    const int* dst = ei + e;

    char* ws = (char*)d_ws;
    auto carve = [&](size_t bytes) {
        char* p = ws;
        ws += (bytes + 255) & ~(size_t)255;
        return p;
    };
    float* h       = (float*)carve((size_t)n * OUT_DIM * sizeof(float)); // 25.6 MB
    float* el      = (float*)carve((size_t)n * sizeof(float));
    float* er      = (float*)carve((size_t)n * sizeof(float));
    int*   deg     = (int*)  carve((size_t)n * sizeof(int));
    int*   offsets = (int*)  carve((size_t)(n + 1) * sizeof(int));
    int*   cursor  = (int*)  carve((size_t)n * sizeof(int));
    int*   esrc    = (int*)  carve((size_t)e * sizeof(int));             // 4 MB

    hipMemsetAsync(deg, 0, (size_t)n * sizeof(int), stream);
    gemm_kernel<<<(n + 15) / 16, 256, 0, stream>>>(X, W, a_l, a_r, h, el, er, n);
    degree_kernel<<<(e + 255) / 256, 256, 0, stream>>>(dst, deg, e);
    scan_kernel<<<1, 1024, 0, stream>>>(deg, offsets, cursor, n);
    scatter_kernel<<<(e + 255) / 256, 256, 0, stream>>>(src, dst, cursor, esrc, e);
    gat_node_kernel<<<(n + 3) / 4, 256, 0, stream>>>(esrc, offsets, el, er, h, out, n);
}

// Round 3
// 350.544 us; speedup vs baseline: 1.5962x; 1.5962x over previous
//
#include <hip/hip_runtime.h>
#include <math.h>

#define IN_DIM 128
#define OUT_DIM 64
#define NEG_SLOPE 0.2f

#define SCAN_ITEMS 4
#define SCAN_BLOCK 1024
#define SCAN_CHUNK (SCAN_BLOCK * SCAN_ITEMS)   // 4096

// ---------------------------------------------------------------- GEMM
// h = X@W, el = h@a_l, er = h@a_r.
// One wave computes 4 rows (lane = output column).
__global__ __launch_bounds__(256) void gemm_kernel(
        const float* __restrict__ X, const float* __restrict__ W,
        const float* __restrict__ a_l, const float* __restrict__ a_r,
        float* __restrict__ h, float* __restrict__ el, float* __restrict__ er, int n)
{
    __shared__ float Wl[IN_DIM * OUT_DIM];    // 32 KB
    __shared__ float Xl[16][IN_DIM];          // 8 KB
    const int tid  = threadIdx.x;
    const int wave = tid >> 6;
    const int lane = tid & 63;

    const float4* W4 = (const float4*)W;
    #pragma unroll
    for (int i = tid; i < IN_DIM * OUT_DIM / 4; i += 256)
        ((float4*)Wl)[i] = W4[i];

    const int row0 = blockIdx.x * 16 + wave * 4;

    #pragma unroll
    for (int i = 0; i < 4; ++i) {
        int r = row0 + i;
        if (r < n) {
            float2 v = ((const float2*)(X + (size_t)r * IN_DIM))[lane];
            Xl[wave * 4 + i][lane * 2]     = v.x;
            Xl[wave * 4 + i][lane * 2 + 1] = v.y;
        }
    }
    __syncthreads();

    float acc[4] = {0.f, 0.f, 0.f, 0.f};
    #pragma unroll 8
    for (int k = 0; k < IN_DIM; ++k) {
        float w = Wl[k * OUT_DIM + lane];
        #pragma unroll
        for (int i = 0; i < 4; ++i)
            acc[i] += Xl[wave * 4 + i][k] * w;
    }

    const float alv = a_l[lane];
    const float arv = a_r[lane];
    #pragma unroll
    for (int i = 0; i < 4; ++i) {
        int r = row0 + i;
        if (r >= n) continue;
        h[(size_t)r * OUT_DIM + lane] = acc[i];
        float vl = acc[i] * alv;
        float vr = acc[i] * arv;
        #pragma unroll
        for (int off = 32; off > 0; off >>= 1) {
            vl += __shfl_xor(vl, off);
            vr += __shfl_xor(vr, off);
        }
        if (lane == 0) { el[r] = vl; er[r] = vr; }
    }
}

// ---------------------------------------------------------------- CSR build
__global__ void degree_kernel(const int* __restrict__ dst, int* __restrict__ deg, int e) {
    int i = blockIdx.x * blockDim.x + threadIdx.x;
    if (i < e) atomicAdd(&deg[dst[i]], 1);
}

// Phase A: per-block sums of deg over SCAN_CHUNK items
__global__ __launch_bounds__(SCAN_BLOCK) void scan_partials_kernel(
        const int* __restrict__ deg, int* __restrict__ bsum, int n)
{
    __shared__ int wsum[SCAN_BLOCK / 64];
    const int tid  = threadIdx.x;
    const int lane = tid & 63;
    const int wave = tid >> 6;
    const int base = blockIdx.x * SCAN_CHUNK + tid * SCAN_ITEMS;

    int s = 0;
    if (base + SCAN_ITEMS <= n) {
        int4 v = *(const int4*)(deg + base);
        s = v.x + v.y + v.z + v.w;
    } else {
        for (int i = 0; i < SCAN_ITEMS; ++i)
            if (base + i < n) s += deg[base + i];
    }
    #pragma unroll
    for (int off = 32; off > 0; off >>= 1) s += __shfl_xor(s, off);
    if (lane == 0) wsum[wave] = s;
    __syncthreads();
    if (tid == 0) {
        int t = 0;
        #pragma unroll
        for (int i = 0; i < SCAN_BLOCK / 64; ++i) t += wsum[i];
        bsum[blockIdx.x] = t;
    }
}

// Phase B: single-wave exclusive scan of nb (<=64) block sums in-place
__global__ __launch_bounds__(64) void scan_bsum_kernel(int* __restrict__ bsum, int nb) {
    const int t = threadIdx.x;
    int orig = (t < nb) ? bsum[t] : 0;
    int v = orig;
    #pragma unroll
    for (int off = 1; off < 64; off <<= 1) {
        int u = __shfl_up(v, off);
        if (t >= off) v += u;
    }
    if (t < nb) bsum[t] = v - orig;   // exclusive
}

// Phase C: per-block exclusive scan + block offset -> offsets, cursor
__global__ __launch_bounds__(SCAN_BLOCK) void scan_apply_kernel(
        const int* __restrict__ deg, const int* __restrict__ bsum,
        int* __restrict__ offsets, int* __restrict__ cursor, int n, int e)
{
    __shared__ int wsum[SCAN_BLOCK / 64];
    const int tid  = threadIdx.x;
    const int lane = tid & 63;
    const int wave = tid >> 6;
    const int base = blockIdx.x * SCAN_CHUNK + tid * SCAN_ITEMS;

    int v[SCAN_ITEMS];
    if (base + SCAN_ITEMS <= n) {
        int4 t4 = *(const int4*)(deg + base);
        v[0] = t4.x; v[1] = t4.y; v[2] = t4.z; v[3] = t4.w;
    } else {
        #pragma unroll
        for (int i = 0; i < SCAN_ITEMS; ++i)
            v[i] = (base + i < n) ? deg[base + i] : 0;
    }
    int s = 0;
    #pragma unroll
    for (int i = 0; i < SCAN_ITEMS; ++i) s += v[i];

    // wave-inclusive scan of per-thread sums
    int incl = s;
    #pragma unroll
    for (int off = 1; off < 64; off <<= 1) {
        int u = __shfl_up(incl, off);
        if (lane >= off) incl += u;
    }
    if (lane == 63) wsum[wave] = incl;
    __syncthreads();
    if (wave == 0 && lane < SCAN_BLOCK / 64) {
        int ws = wsum[lane];
        int wv = ws;
        #pragma unroll
        for (int off = 1; off < SCAN_BLOCK / 64; off <<= 1) {
            int u = __shfl_up(wv, off);
            if (lane >= off) wv += u;
        }
        wsum[lane] = wv - ws;   // exclusive across waves
    }
    __syncthreads();

    int run = bsum[blockIdx.x] + wsum[wave] + (incl - s);
    #pragma unroll
    for (int i = 0; i < SCAN_ITEMS; ++i) {
        int idx = base + i;
        if (idx < n) {
            offsets[idx] = run;
            cursor[idx]  = run;
            run += v[i];
        }
    }
    if (blockIdx.x == 0 && tid == 0) offsets[n] = e;
}

__global__ void scatter_kernel(
        const int* __restrict__ src, const int* __restrict__ dst,
        int* __restrict__ cursor, int* __restrict__ esrc, int e)
{
    int i = blockIdx.x * blockDim.x + threadIdx.x;
    if (i >= e) return;
    int p = atomicAdd(&cursor[dst[i]], 1);
    esrc[p] = src[i];
}

// ---------------------------------------------------------------- fused softmax + aggregate
// One wave per destination node. lane = output channel.
__global__ __launch_bounds__(256) void gat_node_kernel(
        const int* __restrict__ esrc, const int* __restrict__ offsets,
        const float* __restrict__ el, const float* __restrict__ er,
        const float* __restrict__ h, float* __restrict__ out, int n)
{
    const int node = blockIdx.x * 4 + (threadIdx.x >> 6);
    const int lane = threadIdx.x & 63;
    if (node >= n) return;

    const int start = offsets[node];
    const int deg   = offsets[node + 1] - start;

    float acc = 0.f;
    if (deg > 0) {
        const float erd = er[node];
        if (deg <= 64) {
            int   s = 0;
            float x = -INFINITY;
            if (lane < deg) {
                s = esrc[start + lane];
                x = el[s] + erd;
                x = (x > 0.f) ? x : NEG_SLOPE * x;
            }
            float m = x;
            #pragma unroll
            for (int off = 32; off > 0; off >>= 1) m = fmaxf(m, __shfl_xor(m, off));
            float ex = (lane < deg) ? __expf(x - m) : 0.f;
            float dsum = ex;
            #pragma unroll
            for (int off = 32; off > 0; off >>= 1) dsum += __shfl_xor(dsum, off);
            const float inv = 1.f / dsum;

            for (int j = 0; j < deg; ++j) {
                float a  = __shfl(ex, j) * inv;
                int   sj = __shfl(s, j);
                acc += a * h[(size_t)sj * OUT_DIM + lane];
            }
        } else {
            float m = -INFINITY;
            for (int base = 0; base < deg; base += 64) {
                int idx = base + lane;
                if (idx < deg) {
                    int ss = esrc[start + idx];
                    float xx = el[ss] + erd;
                    xx = (xx > 0.f) ? xx : NEG_SLOPE * xx;
                    m = fmaxf(m, xx);
                }
            }
            #pragma unroll
            for (int off = 32; off > 0; off >>= 1) m = fmaxf(m, __shfl_xor(m, off));

            float dsum = 0.f;
            for (int base = 0; base < deg; base += 64) {
                int idx = base + lane;
                if (idx < deg) {
                    int ss = esrc[start + idx];
                    float xx = el[ss] + erd;
                    xx = (xx > 0.f) ? xx : NEG_SLOPE * xx;
                    dsum += __expf(xx - m);
                }
            }
            #pragma unroll
            for (int off = 32; off > 0; off >>= 1) dsum += __shfl_xor(dsum, off);
            const float inv = 1.f / dsum;

            for (int base = 0; base < deg; base += 64) {
                int idx = base + lane;
                int   ss = 0;
                float ex = 0.f;
                if (idx < deg) {
                    ss = esrc[start + idx];
                    float xx = el[ss] + erd;
                    xx = (xx > 0.f) ? xx : NEG_SLOPE * xx;
                    ex = __expf(xx - m);
                }
                int cnt = min(64, deg - base);
                for (int j = 0; j < cnt; ++j) {
                    float a  = __shfl(ex, j) * inv;
                    int   sj = __shfl(ss, j);
                    acc += a * h[(size_t)sj * OUT_DIM + lane];
                }
            }
        }
    }
    out[(size_t)node * OUT_DIM + lane] = acc;
}

// ---------------------------------------------------------------- launch
extern "C" void kernel_launch(void* const* d_in, const int* in_sizes, int n_in,
                              void* d_out, int out_size, void* d_ws, size_t ws_size,
                              hipStream_t stream) {
    const float* X   = (const float*)d_in[0];
    const int*   ei  = (const int*)  d_in[1];
    const float* W   = (const float*)d_in[2];
    const float* a_l = (const float*)d_in[3];
    const float* a_r = (const float*)d_in[4];
    float* out = (float*)d_out;

    const int n = in_sizes[0] / IN_DIM;   // 100000
    const int e = in_sizes[1] / 2;        // 1000000
    const int* src = ei;
    const int* dst = ei + e;

    char* ws = (char*)d_ws;
    auto carve = [&](size_t bytes) {
        char* p = ws;
        ws += (bytes + 255) & ~(size_t)255;
        return p;
    };
    float* h       = (float*)carve((size_t)n * OUT_DIM * sizeof(float)); // 25.6 MB
    float* el      = (float*)carve((size_t)n * sizeof(float));
    float* er      = (float*)carve((size_t)n * sizeof(float));
    int*   deg     = (int*)  carve((size_t)n * sizeof(int));
    int*   offsets = (int*)  carve((size_t)(n + 1) * sizeof(int));
    int*   cursor  = (int*)  carve((size_t)n * sizeof(int));
    int*   esrc    = (int*)  carve((size_t)e * sizeof(int));             // 4 MB
    int*   bsum    = (int*)  carve(64 * sizeof(int));

    const int nscan = (n + SCAN_CHUNK - 1) / SCAN_CHUNK;   // 25 blocks

    hipMemsetAsync(deg, 0, (size_t)n * sizeof(int), stream);
    gemm_kernel<<<(n + 15) / 16, 256, 0, stream>>>(X, W, a_l, a_r, h, el, er, n);
    degree_kernel<<<(e + 255) / 256, 256, 0, stream>>>(dst, deg, e);
    scan_partials_kernel<<<nscan, SCAN_BLOCK, 0, stream>>>(deg, bsum, n);
    scan_bsum_kernel<<<1, 64, 0, stream>>>(bsum, nscan);
    scan_apply_kernel<<<nscan, SCAN_BLOCK, 0, stream>>>(deg, bsum, offsets, cursor, n, e);
    scatter_kernel<<<(e + 255) / 256, 256, 0, stream>>>(src, dst, cursor, esrc, e);
    gat_node_kernel<<<(n + 3) / 4, 256, 0, stream>>>(esrc, offsets, el, er, h, out, n);
}

// Round 4
// 260.322 us; speedup vs baseline: 2.1494x; 1.3466x over previous
//
#include <hip/hip_runtime.h>
#include <math.h>

#define IN_DIM 128
#define OUT_DIM 64
#define NEG_SLOPE 0.2f

#define ROWS_PER_WAVE 8
#define ROWS_PER_BLOCK 32     // 4 waves/block

#define SCAN_ITEMS 4
#define SCAN_BLOCK 1024
#define SCAN_CHUNK (SCAN_BLOCK * SCAN_ITEMS)   // 4096

// ---------------------------------------------------------------- GEMM
// h = X@W, el = h@a_l, er = h@a_r.
// 8 rows per wave; X via ds_read_b128 same-address broadcasts (1 LDS op / 4 k / row),
// W via 4 conflict-free ds_read_b32 per k-quad shared across the 8 rows.
__global__ __launch_bounds__(256) void gemm_kernel(
        const float* __restrict__ X, const float* __restrict__ W,
        const float* __restrict__ a_l, const float* __restrict__ a_r,
        float* __restrict__ h, float* __restrict__ el, float* __restrict__ er, int n)
{
    __shared__ float Wl[IN_DIM * OUT_DIM];               // 32 KB
    __shared__ float Xl[4][ROWS_PER_WAVE * IN_DIM];      // 16 KB
    const int tid  = threadIdx.x;
    const int wave = tid >> 6;
    const int lane = tid & 63;

    // stage W cooperatively (2048 float4, coalesced)
    {
        const float4* W4  = (const float4*)W;
        float4*       Wl4 = (float4*)Wl;
        #pragma unroll
        for (int i = 0; i < 8; ++i)
            Wl4[i * 256 + tid] = W4[i * 256 + tid];
    }

    const int row0 = blockIdx.x * ROWS_PER_BLOCK + wave * ROWS_PER_WAVE;

    // stage this wave's 8 rows (256 float4, coalesced)
    if (row0 + ROWS_PER_WAVE <= n) {
        const float4* Xs = (const float4*)(X + (size_t)row0 * IN_DIM);
        float4*       Xd = (float4*)Xl[wave];
        #pragma unroll
        for (int i = 0; i < 4; ++i)
            Xd[i * 64 + lane] = Xs[i * 64 + lane];
    } else if (row0 < n) {
        // partial tail (only if n % 32 != 0)
        for (int r = 0; r < ROWS_PER_WAVE; ++r) {
            if (row0 + r < n) {
                float2 v = ((const float2*)(X + (size_t)(row0 + r) * IN_DIM))[lane];
                Xl[wave][r * IN_DIM + lane * 2]     = v.x;
                Xl[wave][r * IN_DIM + lane * 2 + 1] = v.y;
            }
        }
    }
    __syncthreads();
    if (row0 >= n) return;

    float acc[ROWS_PER_WAVE] = {};
    const float* Xw = Xl[wave];
    #pragma unroll 2
    for (int kq = 0; kq < IN_DIM / 4; ++kq) {
        const int k = kq * 4;
        const float w0 = Wl[(k    ) * OUT_DIM + lane];
        const float w1 = Wl[(k + 1) * OUT_DIM + lane];
        const float w2 = Wl[(k + 2) * OUT_DIM + lane];
        const float w3 = Wl[(k + 3) * OUT_DIM + lane];
        #pragma unroll
        for (int r = 0; r < ROWS_PER_WAVE; ++r) {
            const float4 x = *(const float4*)(Xw + r * IN_DIM + k);  // broadcast
            acc[r] = fmaf(x.x, w0, acc[r]);
            acc[r] = fmaf(x.y, w1, acc[r]);
            acc[r] = fmaf(x.z, w2, acc[r]);
            acc[r] = fmaf(x.w, w3, acc[r]);
        }
    }

    const float alv = a_l[lane];
    const float arv = a_r[lane];
    #pragma unroll
    for (int r = 0; r < ROWS_PER_WAVE; ++r) {
        const int row = row0 + r;
        if (row >= n) break;
        h[(size_t)row * OUT_DIM + lane] = acc[r];
        float vl = acc[r] * alv;
        float vr = acc[r] * arv;
        #pragma unroll
        for (int off = 32; off > 0; off >>= 1) {
            vl += __shfl_xor(vl, off);
            vr += __shfl_xor(vr, off);
        }
        if (lane == 0) { el[row] = vl; er[row] = vr; }
    }
}

// ---------------------------------------------------------------- CSR build
// degree + per-edge rank in one atomic
__global__ void degree_rank_kernel(const int* __restrict__ dst, int* __restrict__ deg,
                                   int* __restrict__ erank, int e) {
    int i = blockIdx.x * blockDim.x + threadIdx.x;
    if (i < e) erank[i] = atomicAdd(&deg[dst[i]], 1);
}

// Phase A: per-block sums of deg over SCAN_CHUNK items
__global__ __launch_bounds__(SCAN_BLOCK) void scan_partials_kernel(
        const int* __restrict__ deg, int* __restrict__ bsum, int n)
{
    __shared__ int wsum[SCAN_BLOCK / 64];
    const int tid  = threadIdx.x;
    const int lane = tid & 63;
    const int wave = tid >> 6;
    const int base = blockIdx.x * SCAN_CHUNK + tid * SCAN_ITEMS;

    int s = 0;
    if (base + SCAN_ITEMS <= n) {
        int4 v = *(const int4*)(deg + base);
        s = v.x + v.y + v.z + v.w;
    } else {
        for (int i = 0; i < SCAN_ITEMS; ++i)
            if (base + i < n) s += deg[base + i];
    }
    #pragma unroll
    for (int off = 32; off > 0; off >>= 1) s += __shfl_xor(s, off);
    if (lane == 0) wsum[wave] = s;
    __syncthreads();
    if (tid == 0) {
        int t = 0;
        #pragma unroll
        for (int i = 0; i < SCAN_BLOCK / 64; ++i) t += wsum[i];
        bsum[blockIdx.x] = t;
    }
}

// Phase B: single-wave exclusive scan of nb (<=64) block sums in-place
__global__ __launch_bounds__(64) void scan_bsum_kernel(int* __restrict__ bsum, int nb) {
    const int t = threadIdx.x;
    int orig = (t < nb) ? bsum[t] : 0;
    int v = orig;
    #pragma unroll
    for (int off = 1; off < 64; off <<= 1) {
        int u = __shfl_up(v, off);
        if (t >= off) v += u;
    }
    if (t < nb) bsum[t] = v - orig;   // exclusive
}

// Phase C: per-block exclusive scan + block offset -> offsets
__global__ __launch_bounds__(SCAN_BLOCK) void scan_apply_kernel(
        const int* __restrict__ deg, const int* __restrict__ bsum,
        int* __restrict__ offsets, int n, int e)
{
    __shared__ int wsum[SCAN_BLOCK / 64];
    const int tid  = threadIdx.x;
    const int lane = tid & 63;
    const int wave = tid >> 6;
    const int base = blockIdx.x * SCAN_CHUNK + tid * SCAN_ITEMS;

    int v[SCAN_ITEMS];
    if (base + SCAN_ITEMS <= n) {
        int4 t4 = *(const int4*)(deg + base);
        v[0] = t4.x; v[1] = t4.y; v[2] = t4.z; v[3] = t4.w;
    } else {
        #pragma unroll
        for (int i = 0; i < SCAN_ITEMS; ++i)
            v[i] = (base + i < n) ? deg[base + i] : 0;
    }
    int s = 0;
    #pragma unroll
    for (int i = 0; i < SCAN_ITEMS; ++i) s += v[i];

    int incl = s;
    #pragma unroll
    for (int off = 1; off < 64; off <<= 1) {
        int u = __shfl_up(incl, off);
        if (lane >= off) incl += u;
    }
    if (lane == 63) wsum[wave] = incl;
    __syncthreads();
    if (wave == 0 && lane < SCAN_BLOCK / 64) {
        int ws = wsum[lane];
        int wv = ws;
        #pragma unroll
        for (int off = 1; off < SCAN_BLOCK / 64; off <<= 1) {
            int u = __shfl_up(wv, off);
            if (lane >= off) wv += u;
        }
        wsum[lane] = wv - ws;
    }
    __syncthreads();

    int run = bsum[blockIdx.x] + wsum[wave] + (incl - s);
    #pragma unroll
    for (int i = 0; i < SCAN_ITEMS; ++i) {
        int idx = base + i;
        if (idx < n) {
            offsets[idx] = run;
            run += v[i];
        }
    }
    if (blockIdx.x == 0 && tid == 0) offsets[n] = e;
}

// atomic-free scatter using precomputed rank
__global__ void scatter_kernel(
        const int* __restrict__ src, const int* __restrict__ dst,
        const int* __restrict__ offsets, const int* __restrict__ erank,
        int* __restrict__ esrc, int e)
{
    int i = blockIdx.x * blockDim.x + threadIdx.x;
    if (i >= e) return;
    esrc[offsets[dst[i]] + erank[i]] = src[i];
}

// ---------------------------------------------------------------- fused softmax + aggregate
// One wave per destination node. lane = output channel. 4-way unrolled gather.
__global__ __launch_bounds__(256) void gat_node_kernel(
        const int* __restrict__ esrc, const int* __restrict__ offsets,
        const float* __restrict__ el, const float* __restrict__ er,
        const float* __restrict__ h, float* __restrict__ out, int n)
{
    const int node = blockIdx.x * 4 + (threadIdx.x >> 6);
    const int lane = threadIdx.x & 63;
    if (node >= n) return;

    const int start = offsets[node];
    const int deg   = offsets[node + 1] - start;

    float acc = 0.f;
    if (deg > 0) {
        const float erd = er[node];
        if (deg <= 64) {
            int   s = 0;
            float x = -INFINITY;
            if (lane < deg) {
                s = esrc[start + lane];
                x = el[s] + erd;
                x = (x > 0.f) ? x : NEG_SLOPE * x;
            }
            float m = x;
            #pragma unroll
            for (int off = 32; off > 0; off >>= 1) m = fmaxf(m, __shfl_xor(m, off));
            float ex = (lane < deg) ? __expf(x - m) : 0.f;
            float dsum = ex;
            #pragma unroll
            for (int off = 32; off > 0; off >>= 1) dsum += __shfl_xor(dsum, off);
            const float a = ex * (1.f / dsum);     // per-lane alpha

            float acc0 = 0.f, acc1 = 0.f, acc2 = 0.f, acc3 = 0.f;
            int j = 0;
            for (; j + 4 <= deg; j += 4) {
                const float a0 = __shfl(a, j),     a1 = __shfl(a, j + 1);
                const float a2 = __shfl(a, j + 2), a3 = __shfl(a, j + 3);
                const int   s0 = __shfl(s, j),     s1 = __shfl(s, j + 1);
                const int   s2 = __shfl(s, j + 2), s3 = __shfl(s, j + 3);
                const float h0 = h[(size_t)s0 * OUT_DIM + lane];
                const float h1 = h[(size_t)s1 * OUT_DIM + lane];
                const float h2 = h[(size_t)s2 * OUT_DIM + lane];
                const float h3 = h[(size_t)s3 * OUT_DIM + lane];
                acc0 = fmaf(a0, h0, acc0);
                acc1 = fmaf(a1, h1, acc1);
                acc2 = fmaf(a2, h2, acc2);
                acc3 = fmaf(a3, h3, acc3);
            }
            for (; j < deg; ++j) {
                const float aj = __shfl(a, j);
                const int   sj = __shfl(s, j);
                acc0 = fmaf(aj, h[(size_t)sj * OUT_DIM + lane], acc0);
            }
            acc = (acc0 + acc1) + (acc2 + acc3);
        } else {
            // general chunked path (deg > 64, rare)
            float m = -INFINITY;
            for (int base = 0; base < deg; base += 64) {
                int idx = base + lane;
                if (idx < deg) {
                    int ss = esrc[start + idx];
                    float xx = el[ss] + erd;
                    xx = (xx > 0.f) ? xx : NEG_SLOPE * xx;
                    m = fmaxf(m, xx);
                }
            }
            #pragma unroll
            for (int off = 32; off > 0; off >>= 1) m = fmaxf(m, __shfl_xor(m, off));

            float dsum = 0.f;
            for (int base = 0; base < deg; base += 64) {
                int idx = base + lane;
                if (idx < deg) {
                    int ss = esrc[start + idx];
                    float xx = el[ss] + erd;
                    xx = (xx > 0.f) ? xx : NEG_SLOPE * xx;
                    dsum += __expf(xx - m);
                }
            }
            #pragma unroll
            for (int off = 32; off > 0; off >>= 1) dsum += __shfl_xor(dsum, off);
            const float inv = 1.f / dsum;

            float acc0 = 0.f, acc1 = 0.f, acc2 = 0.f, acc3 = 0.f;
            for (int base = 0; base < deg; base += 64) {
                int idx = base + lane;
                int   ss = 0;
                float av = 0.f;
                if (idx < deg) {
                    ss = esrc[start + idx];
                    float xx = el[ss] + erd;
                    xx = (xx > 0.f) ? xx : NEG_SLOPE * xx;
                    av = __expf(xx - m) * inv;
                }
                const int cnt = min(64, deg - base);
                int j = 0;
                for (; j + 4 <= cnt; j += 4) {
                    const float a0 = __shfl(av, j),     a1 = __shfl(av, j + 1);
                    const float a2 = __shfl(av, j + 2), a3 = __shfl(av, j + 3);
                    const int   s0 = __shfl(ss, j),     s1 = __shfl(ss, j + 1);
                    const int   s2 = __shfl(ss, j + 2), s3 = __shfl(ss, j + 3);
                    acc0 = fmaf(a0, h[(size_t)s0 * OUT_DIM + lane], acc0);
                    acc1 = fmaf(a1, h[(size_t)s1 * OUT_DIM + lane], acc1);
                    acc2 = fmaf(a2, h[(size_t)s2 * OUT_DIM + lane], acc2);
                    acc3 = fmaf(a3, h[(size_t)s3 * OUT_DIM + lane], acc3);
                }
                for (; j < cnt; ++j) {
                    const float aj = __shfl(av, j);
                    const int   sj = __shfl(ss, j);
                    acc0 = fmaf(aj, h[(size_t)sj * OUT_DIM + lane], acc0);
                }
            }
            acc = (acc0 + acc1) + (acc2 + acc3);
        }
    }
    out[(size_t)node * OUT_DIM + lane] = acc;
}

// ---------------------------------------------------------------- launch
extern "C" void kernel_launch(void* const* d_in, const int* in_sizes, int n_in,
                              void* d_out, int out_size, void* d_ws, size_t ws_size,
                              hipStream_t stream) {
    const float* X   = (const float*)d_in[0];
    const int*   ei  = (const int*)  d_in[1];
    const float* W   = (const float*)d_in[2];
    const float* a_l = (const float*)d_in[3];
    const float* a_r = (const float*)d_in[4];
    float* out = (float*)d_out;

    const int n = in_sizes[0] / IN_DIM;   // 100000
    const int e = in_sizes[1] / 2;        // 1000000
    const int* src = ei;
    const int* dst = ei + e;

    char* ws = (char*)d_ws;
    auto carve = [&](size_t bytes) {
        char* p = ws;
        ws += (bytes + 255) & ~(size_t)255;
        return p;
    };
    float* h       = (float*)carve((size_t)n * OUT_DIM * sizeof(float)); // 25.6 MB
    float* el      = (float*)carve((size_t)n * sizeof(float));
    float* er      = (float*)carve((size_t)n * sizeof(float));
    int*   deg     = (int*)  carve((size_t)n * sizeof(int));
    int*   offsets = (int*)  carve((size_t)(n + 1) * sizeof(int));
    int*   erank   = (int*)  carve((size_t)e * sizeof(int));             // 4 MB
    int*   esrc    = (int*)  carve((size_t)e * sizeof(int));             // 4 MB
    int*   bsum    = (int*)  carve(64 * sizeof(int));

    const int nscan = (n + SCAN_CHUNK - 1) / SCAN_CHUNK;   // 25 blocks

    hipMemsetAsync(deg, 0, (size_t)n * sizeof(int), stream);
    gemm_kernel<<<(n + ROWS_PER_BLOCK - 1) / ROWS_PER_BLOCK, 256, 0, stream>>>(
        X, W, a_l, a_r, h, el, er, n);
    degree_rank_kernel<<<(e + 255) / 256, 256, 0, stream>>>(dst, deg, erank, e);
    scan_partials_kernel<<<nscan, SCAN_BLOCK, 0, stream>>>(deg, bsum, n);
    scan_bsum_kernel<<<1, 64, 0, stream>>>(bsum, nscan);
    scan_apply_kernel<<<nscan, SCAN_BLOCK, 0, stream>>>(deg, bsum, offsets, n, e);
    scatter_kernel<<<(e + 255) / 256, 256, 0, stream>>>(src, dst, offsets, erank, esrc, e);
    gat_node_kernel<<<(n + 3) / 4, 256, 0, stream>>>(esrc, offsets, el, er, h, out, n);
}